// Round 3
// baseline (461.567 us; speedup 1.0000x reference)
//
#include <hip/hip_runtime.h>
#include <hip/hip_bf16.h>

#define SEQ 2048
#define DM  1024

typedef __attribute__((ext_vector_type(8)))  short frag8;   // 8 bf16 (4 VGPR) MFMA A/B
typedef __attribute__((ext_vector_type(4)))  float f32x4;   // 16x16 C/D
typedef __attribute__((ext_vector_type(16))) float f32x16;  // 32x32 C/D

// ---------- bf16 split helpers ----------
__device__ __forceinline__ ushort f2bf(float x) {            // RNE
    union { float f; unsigned u; } c; c.f = x;
    return (ushort)((c.u + 0x7FFFu + ((c.u >> 16) & 1u)) >> 16);
}
__device__ __forceinline__ float bf2f(ushort h) {
    union { unsigned u; float f; } c; c.u = ((unsigned)h) << 16;
    return c.f;
}
__device__ __forceinline__ void split2(float x, ushort& h, ushort& l) {  // RNE hi
    h = f2bf(x);
    l = f2bf(x - bf2f(h));
}
__device__ __forceinline__ void tsplit(float x, ushort& h, ushort& l) {  // trunc hi (cheap)
    union { float f; unsigned u; } c; c.f = x;
    h = (ushort)(c.u >> 16);
    union { unsigned u; float f; } m; m.u = c.u & 0xFFFF0000u;
    union { float f; unsigned u; } d; d.f = x - m.f;
    l = (ushort)(d.u >> 16);
}

// ---------- async global->LDS (16B per lane, per-lane global addr, uniform LDS base) ----------
__device__ __forceinline__ void gload16(const void* g, void* l) {
    __builtin_amdgcn_global_load_lds(
        (const __attribute__((address_space(1))) unsigned*)(uintptr_t)g,
        (__attribute__((address_space(3))) unsigned*)(uintptr_t)l, 16, 0, 0);
}

// ============================================================================
// split_all: fp32 -> bf16 hi/lo arenas. x (4M elems) -> xh/xl; wq|wk|wv|wo -> wh/wl.
// ============================================================================
__global__ __launch_bounds__(256)
void split_all(const float* __restrict__ x,  const float* __restrict__ wq,
               const float* __restrict__ wk, const float* __restrict__ wv,
               const float* __restrict__ wo,
               ushort* __restrict__ xh, ushort* __restrict__ xl,
               ushort* __restrict__ wh, ushort* __restrict__ wl)
{
    const int NX4 = (2 * SEQ * DM) / 4;     // 1,048,576 float4
    const int NW4 = (DM * DM) / 4;          //   262,144 float4 per weight
    const int total = NX4 + 4 * NW4;
    for (int i = blockIdx.x * 256 + threadIdx.x; i < total; i += gridDim.x * 256) {
        float4 v; ushort4 *dh, *dl;
        if (i < NX4) {
            v = ((const float4*)x)[i];
            dh = (ushort4*)xh + i; dl = (ushort4*)xl + i;
        } else {
            const int j = i - NX4;
            const int wi = j >> 18;                 // /NW4
            const int jo = j & (NW4 - 1);
            const float* ws_ = (wi == 0) ? wq : (wi == 1) ? wk : (wi == 2) ? wv : wo;
            v = ((const float4*)ws_)[jo];
            dh = (ushort4*)wh + j; dl = (ushort4*)wl + j;
        }
        ushort4 h, l;
        split2(v.x, h.x, l.x); split2(v.y, h.y, l.y);
        split2(v.z, h.z, l.z); split2(v.w, h.w, l.w);
        *dh = h; *dl = l;
    }
}

// ============================================================================
// GEMM v2: C = A * B^T (+bias), A rows m (contig k), B rows n (contig k),
// both pre-split bf16 hi/lo. Tile 128x128, 4 waves (2x2), BK=32,
// mfma_f32_32x32x16_bf16 x3, global_load_lds staging, 2-phase dbuf.
// LDS tile row: 8 chunks of 16B; logical c: 0..3 = hi k/8, 4..7 = lo.
// physical chunk p = c ^ (r&7)  (balanced-bank swizzle, both sides).
// MODE 0: fused QKV (M=3072; m/1024 selects Q/K/V epilogue)
// MODE 1: O-proj -> fp32 out
// ============================================================================
template<int MODE>
__global__ __launch_bounds__(256, 2)
void gemm2(const ushort* __restrict__ Ah, const ushort* __restrict__ Al,
           const ushort* __restrict__ Bh, const ushort* __restrict__ Bl,
           const float* __restrict__ b0, const float* __restrict__ b1,
           const float* __restrict__ b2,
           ushort* __restrict__ Qh, ushort* __restrict__ Ql,
           ushort* __restrict__ Kh, ushort* __restrict__ Kl,
           ushort* __restrict__ Vh, ushort* __restrict__ Vl,
           float* __restrict__ outf)
{
    __shared__ ushort As[2][128 * 64];
    __shared__ ushort Bs[2][128 * 64];

    const int t = threadIdx.x, w = t >> 6, lane = t & 63;
    const int m0 = blockIdx.x * 128, n0 = blockIdx.y * 128;
    const int wm = (w >> 1) * 64, wn = (w & 1) * 64;

    auto stage = [&](int buf, int k0) {
#pragma unroll
        for (int i = 0; i < 8; ++i) {
            const int gi = w * 8 + i;                    // 0..31
            const int rt = (gi & 15) * 8 + (lane >> 3);  // row in tile
            const int c  = (lane & 7) ^ (rt & 7);        // logical chunk for this slot
            const bool isA = gi < 16;
            const ushort* src = isA ? (c < 4 ? Ah : Al) : (c < 4 ? Bh : Bl);
            const size_t go = (size_t)((isA ? m0 : n0) + rt) * DM + k0 + (c & 3) * 8;
            ushort* dst = (isA ? As[buf] : Bs[buf]) + (gi & 15) * 8 * 64;
            gload16(src + go, dst);
        }
    };

    f32x16 acc[2][2];
#pragma unroll
    for (int i = 0; i < 2; ++i)
#pragma unroll
        for (int j = 0; j < 2; ++j)
#pragma unroll
            for (int r = 0; r < 16; ++r) acc[i][j][r] = 0.f;

    stage(0, 0);
    __syncthreads();

    for (int ks = 0; ks < 32; ++ks) {
        const int buf = ks & 1;
        if (ks < 31) stage(buf ^ 1, (ks + 1) * 32);

        frag8 af[2][2][2], bf[2][2][2];   // [mi/ni][ksub][hi/lo]
#pragma unroll
        for (int mi = 0; mi < 2; ++mi)
#pragma unroll
            for (int kq = 0; kq < 2; ++kq) {
                const int r = wm + mi * 32 + (lane & 31);
                const int c = kq * 2 + (lane >> 5);
                af[mi][kq][0] = *(const frag8*)&As[buf][r * 64 + ((c       ^ (r & 7)) << 3)];
                af[mi][kq][1] = *(const frag8*)&As[buf][r * 64 + (((c + 4) ^ (r & 7)) << 3)];
            }
#pragma unroll
        for (int ni = 0; ni < 2; ++ni)
#pragma unroll
            for (int kq = 0; kq < 2; ++kq) {
                const int r = wn + ni * 32 + (lane & 31);
                const int c = kq * 2 + (lane >> 5);
                bf[ni][kq][0] = *(const frag8*)&Bs[buf][r * 64 + ((c       ^ (r & 7)) << 3)];
                bf[ni][kq][1] = *(const frag8*)&Bs[buf][r * 64 + (((c + 4) ^ (r & 7)) << 3)];
            }
#pragma unroll
        for (int kq = 0; kq < 2; ++kq)
#pragma unroll
            for (int mi = 0; mi < 2; ++mi)
#pragma unroll
                for (int ni = 0; ni < 2; ++ni) {
                    acc[mi][ni] = __builtin_amdgcn_mfma_f32_32x32x16_bf16(af[mi][kq][0], bf[ni][kq][0], acc[mi][ni], 0, 0, 0);
                    acc[mi][ni] = __builtin_amdgcn_mfma_f32_32x32x16_bf16(af[mi][kq][0], bf[ni][kq][1], acc[mi][ni], 0, 0, 0);
                    acc[mi][ni] = __builtin_amdgcn_mfma_f32_32x32x16_bf16(af[mi][kq][1], bf[ni][kq][0], acc[mi][ni], 0, 0, 0);
                }
        __syncthreads();
    }

    // ---- epilogue: C row m = (reg&3)+8*(reg>>2)+4*(lane>>5), col n = lane&31 ----
    const int g = lane >> 5;
    const int mode = m0 >> 10;   // 0=Q 1=K 2=V (MODE 0 only)
#pragma unroll
    for (int mi = 0; mi < 2; ++mi)
#pragma unroll
        for (int ni = 0; ni < 2; ++ni) {
            const int col = n0 + wn + ni * 32 + (lane & 31);
            const int b = col >> 11, s = col & 2047;
            f32x16 v = acc[mi][ni];
#pragma unroll
            for (int q2 = 0; q2 < 4; ++q2) {
                const int row = m0 + wm + mi * 32 + q2 * 8 + g * 4;   // 4 consecutive
                if (MODE == 1) {
                    float4 o;
                    o.x = v[q2 * 4 + 0] + b0[row + 0];
                    o.y = v[q2 * 4 + 1] + b0[row + 1];
                    o.z = v[q2 * 4 + 2] + b0[row + 2];
                    o.w = v[q2 * 4 + 3] + b0[row + 3];
                    *(float4*)&outf[(size_t)col * DM + row] = o;
                } else {
                    const int e = row & 1023;
                    const int h = e >> 6, dk = e & 63;
                    const float* bp = (mode == 0) ? b0 : (mode == 1) ? b1 : b2;
                    const float sc = (mode == 0) ? 0.125f : 1.0f;
                    float v0 = (v[q2 * 4 + 0] + bp[e + 0]) * sc;
                    float v1 = (v[q2 * 4 + 1] + bp[e + 1]) * sc;
                    float v2 = (v[q2 * 4 + 2] + bp[e + 2]) * sc;
                    float v3 = (v[q2 * 4 + 3] + bp[e + 3]) * sc;
                    ushort4 hi, lo;
                    split2(v0, hi.x, lo.x); split2(v1, hi.y, lo.y);
                    split2(v2, hi.z, lo.z); split2(v3, hi.w, lo.w);
                    const int bh = b * 16 + h;
                    if (mode == 0) {
                        const size_t off = ((size_t)bh * SEQ + s) * 64 + dk;
                        *(ushort4*)&Qh[off] = hi; *(ushort4*)&Ql[off] = lo;
                    } else if (mode == 1) {
                        const size_t off = ((size_t)bh * SEQ + s) * 64 + dk;
                        *(ushort4*)&Kh[off] = hi; *(ushort4*)&Kl[off] = lo;
                    } else {   // V transposed: [bh][dk][s]
                        const size_t o0 = ((size_t)bh * 64 + dk) * SEQ + s;
                        Vh[o0]            = hi.x; Vl[o0]            = lo.x;
                        Vh[o0 + SEQ]      = hi.y; Vl[o0 + SEQ]      = lo.y;
                        Vh[o0 + 2 * SEQ]  = hi.z; Vl[o0 + 2 * SEQ]  = lo.z;
                        Vh[o0 + 3 * SEQ]  = hi.w; Vl[o0 + 3 * SEQ]  = lo.w;
                    }
                }
            }
        }
}

// ============================================================================
// Flash attention, bf16x3, swapped QK^T; T14 async-stage; trunc P-split.
// Block = (b,h,qtile 128); 4 waves x 32 q. Writes ctx as bf16 hi/lo.
// ============================================================================
__global__ __launch_bounds__(256, 2)
void attn_k(const ushort* __restrict__ Qh, const ushort* __restrict__ Ql,
            const ushort* __restrict__ Kh, const ushort* __restrict__ Kl,
            const ushort* __restrict__ Vh, const ushort* __restrict__ Vl,
            const int* __restrict__ mask,
            ushort* __restrict__ ch, ushort* __restrict__ cl)
{
    __shared__ ushort Ks[64 * 128];     // [key][16 chunks: hi 0..7 | lo 8..15] over dk
    __shared__ ushort Vs[64 * 128];     // [d][16 chunks] over keys
    __shared__ ushort Ps[4][32 * 128];  // per-wave P^T [q][16 chunks] over keys

    const int t = threadIdx.x, w = t >> 6, lane = t & 63;
    const int bh = blockIdx.x >> 4, qt = blockIdx.x & 15;
    const int b = bh >> 4, h = bh & 15;
    const int q0 = qt * 128 + w * 32;
    const size_t base = (size_t)bh * SEQ * 64;

    // Q fragments (B-operand): col q = lane&15, 8 contiguous dk
    frag8 qfh[2][2], qfl[2][2];
#pragma unroll
    for (int nf = 0; nf < 2; ++nf)
#pragma unroll
        for (int kb = 0; kb < 2; ++kb) {
            const size_t off = base + (size_t)(q0 + nf * 16 + (lane & 15)) * 64
                             + kb * 32 + ((lane >> 4) << 3);
            qfh[nf][kb] = *(const frag8*)&Qh[off];
            qfl[nf][kb] = *(const frag8*)&Ql[off];
        }

    int msk[2];
#pragma unroll
    for (int nf = 0; nf < 2; ++nf)
        msk[nf] = mask[b * SEQ + q0 + nf * 16 + (lane & 15)];

    float m_run[2] = {-1e30f, -1e30f}, l_run[2] = {0.f, 0.f};
    f32x4 acc[4][2];
#pragma unroll
    for (int df = 0; df < 4; ++df)
#pragma unroll
        for (int nf = 0; nf < 2; ++nf) acc[df][nf] = f32x4{0.f, 0.f, 0.f, 0.f};

    frag8 sK[4], sV[4];
    auto stage_load = [&](int kt) {
#pragma unroll
        for (int j = 0; j < 4; ++j) {
            const int i = j * 256 + t, r = i >> 4, cc = i & 15, cli = cc & 7;
            const ushort* kp = (cc < 8) ? Kh : Kl;
            const ushort* vp = (cc < 8) ? Vh : Vl;
            sK[j] = *(const frag8*)&kp[base + (size_t)(kt * 64 + r) * 64 + (cli << 3)];
            sV[j] = *(const frag8*)&vp[base + (size_t)r * SEQ + kt * 64 + (cli << 3)];
        }
    };
    auto stage_write = [&]() {
#pragma unroll
        for (int j = 0; j < 4; ++j) {
            const int i = j * 256 + t, r = i >> 4, cc = i & 15, cli = cc & 7;
            const int ph = (cli ^ (r & 7)) + (cc & 8);
            *(frag8*)&Ks[r * 128 + (ph << 3)] = sK[j];
            *(frag8*)&Vs[r * 128 + (ph << 3)] = sV[j];
        }
    };

    stage_load(0); stage_write();
    __syncthreads();

    for (int kt = 0; kt < SEQ / 64; ++kt) {
        if (kt < SEQ / 64 - 1) stage_load(kt + 1);   // T14: issue early

        // ---- S^T = K * Q^T ----
        f32x4 st[4][2];
#pragma unroll
        for (int mf = 0; mf < 4; ++mf)
#pragma unroll
            for (int nf = 0; nf < 2; ++nf) st[mf][nf] = f32x4{0.f, 0.f, 0.f, 0.f};
#pragma unroll
        for (int mf = 0; mf < 4; ++mf) {
            const int r = mf * 16 + (lane & 15);
            const int cb = lane >> 4;
#pragma unroll
            for (int kb = 0; kb < 2; ++kb) {
                const int c = kb * 4 + cb;
                const int p = c ^ (r & 7);
                frag8 kfh = *(const frag8*)&Ks[r * 128 + (p << 3)];
                frag8 kfl = *(const frag8*)&Ks[r * 128 + ((p + 8) << 3)];
#pragma unroll
                for (int nf = 0; nf < 2; ++nf) {
                    st[mf][nf] = __builtin_amdgcn_mfma_f32_16x16x32_bf16(kfh, qfh[nf][kb], st[mf][nf], 0, 0, 0);
                    st[mf][nf] = __builtin_amdgcn_mfma_f32_16x16x32_bf16(kfh, qfl[nf][kb], st[mf][nf], 0, 0, 0);
                    st[mf][nf] = __builtin_amdgcn_mfma_f32_16x16x32_bf16(kfl, qfh[nf][kb], st[mf][nf], 0, 0, 0);
                }
            }
        }

        // ---- online softmax over keys (per q-column) ----
        float corr[2];
#pragma unroll
        for (int nf = 0; nf < 2; ++nf) {
            if (msk[nf] == 0) {
#pragma unroll
                for (int mf = 0; mf < 4; ++mf) st[mf][nf] = f32x4{0.f, 0.f, 0.f, 0.f};
            }
            float mx = -1e30f;
#pragma unroll
            for (int mf = 0; mf < 4; ++mf)
#pragma unroll
                for (int r4 = 0; r4 < 4; ++r4) mx = fmaxf(mx, st[mf][nf][r4]);
            mx = fmaxf(mx, __shfl_xor(mx, 16));
            mx = fmaxf(mx, __shfl_xor(mx, 32));
            const float mnew = fmaxf(m_run[nf], mx);
            corr[nf] = __expf(m_run[nf] - mnew);
            m_run[nf] = mnew;
            float ss = 0.f;
#pragma unroll
            for (int mf = 0; mf < 4; ++mf)
#pragma unroll
                for (int r4 = 0; r4 < 4; ++r4) {
                    const float p = __expf(st[mf][nf][r4] - mnew);
                    st[mf][nf][r4] = p; ss += p;
                }
            ss += __shfl_xor(ss, 16);
            ss += __shfl_xor(ss, 32);
            l_run[nf] = l_run[nf] * corr[nf] + ss;
#pragma unroll
            for (int df = 0; df < 4; ++df)
#pragma unroll
                for (int r4 = 0; r4 < 4; ++r4) acc[df][nf][r4] *= corr[nf];
        }

        // ---- P^T -> per-wave LDS (truncation split) ----
#pragma unroll
        for (int nf = 0; nf < 2; ++nf) {
            const int q = nf * 16 + (lane & 15);
#pragma unroll
            for (int mf = 0; mf < 4; ++mf) {
                const int key0 = mf * 16 + ((lane >> 4) << 2);
                ushort4 hi, lo;
                tsplit(st[mf][nf][0], hi.x, lo.x);
                tsplit(st[mf][nf][1], hi.y, lo.y);
                tsplit(st[mf][nf][2], hi.z, lo.z);
                tsplit(st[mf][nf][3], hi.w, lo.w);
                const int c = key0 >> 3, sub = key0 & 7;
                const int p = c ^ (q & 7);
                *(ushort4*)&Ps[w][q * 128 + (p << 3) + sub] = hi;
                *(ushort4*)&Ps[w][q * 128 + ((p + 8) << 3) + sub] = lo;
            }
        }

        // ---- ctx^T += V^T * P^T ----
        frag8 pfh[2][2], pfl[2][2];
#pragma unroll
        for (int nf = 0; nf < 2; ++nf) {
            const int q = nf * 16 + (lane & 15);
            const int cb = lane >> 4;
#pragma unroll
            for (int kb = 0; kb < 2; ++kb) {
                const int c = kb * 4 + cb;
                const int p = c ^ (q & 7);
                pfh[nf][kb] = *(const frag8*)&Ps[w][q * 128 + (p << 3)];
                pfl[nf][kb] = *(const frag8*)&Ps[w][q * 128 + ((p + 8) << 3)];
            }
        }
#pragma unroll
        for (int df = 0; df < 4; ++df) {
            const int r = df * 16 + (lane & 15);
            const int cb = lane >> 4;
#pragma unroll
            for (int kb = 0; kb < 2; ++kb) {
                const int c = kb * 4 + cb;
                const int p = c ^ (r & 7);
                frag8 vfh = *(const frag8*)&Vs[r * 128 + (p << 3)];
                frag8 vfl = *(const frag8*)&Vs[r * 128 + ((p + 8) << 3)];
#pragma unroll
                for (int nf = 0; nf < 2; ++nf) {
                    acc[df][nf] = __builtin_amdgcn_mfma_f32_16x16x32_bf16(vfh, pfh[nf][kb], acc[df][nf], 0, 0, 0);
                    acc[df][nf] = __builtin_amdgcn_mfma_f32_16x16x32_bf16(vfh, pfl[nf][kb], acc[df][nf], 0, 0, 0);
                    acc[df][nf] = __builtin_amdgcn_mfma_f32_16x16x32_bf16(vfl, pfh[nf][kb], acc[df][nf], 0, 0, 0);
                }
            }
        }

        __syncthreads();                          // all reads of Ks/Vs done
        if (kt < SEQ / 64 - 1) {
            stage_write();                        // T14: write late (vmcnt drained by barrier)
            __syncthreads();
        }
    }

    // ---- epilogue: ctx as bf16 hi/lo, [b][s][h*64+d] ----
#pragma unroll
    for (int nf = 0; nf < 2; ++nf) {
        const float inv = 1.0f / l_run[nf];
        const int s = q0 + nf * 16 + (lane & 15);
#pragma unroll
        for (int df = 0; df < 4; ++df) {
            const int e0 = h * 64 + df * 16 + ((lane >> 4) << 2);
            ushort4 hi, lo;
            split2(acc[df][nf][0] * inv, hi.x, lo.x);
            split2(acc[df][nf][1] * inv, hi.y, lo.y);
            split2(acc[df][nf][2] * inv, hi.z, lo.z);
            split2(acc[df][nf][3] * inv, hi.w, lo.w);
            const size_t off = (size_t)(b * SEQ + s) * DM + e0;
            *(ushort4*)&ch[off] = hi;
            *(ushort4*)&cl[off] = lo;
        }
    }
}

extern "C" void kernel_launch(void* const* d_in, const int* in_sizes, int n_in,
                              void* d_out, int out_size, void* d_ws, size_t ws_size,
                              hipStream_t stream)
{
    const float* x  = (const float*)d_in[0];
    const int* mask = (const int*)d_in[1];
    const float* wq = (const float*)d_in[2];
    const float* bq = (const float*)d_in[3];
    const float* wk = (const float*)d_in[4];
    const float* bk = (const float*)d_in[5];
    const float* wv = (const float*)d_in[6];
    const float* bv = (const float*)d_in[7];
    const float* wo = (const float*)d_in[8];
    const float* bo = (const float*)d_in[9];
    float* out = (float*)d_out;

    const size_t M1 = 1024 * 1024;      // 1M elements
    ushort* W = (ushort*)d_ws;          // 80 MB arena
    ushort* xh = W;                     // 4M  (doubles as ctx_hi after attn)
    ushort* xl = W + 4 * M1;            // 4M  (ctx_lo)
    ushort* wh = W + 8 * M1;            // 4M: wq|wk|wv|wo
    ushort* wl = W + 12 * M1;
    ushort* Qh = W + 16 * M1;
    ushort* Ql = W + 20 * M1;
    ushort* Kh = W + 24 * M1;
    ushort* Kl = W + 28 * M1;
    ushort* Vh = W + 32 * M1;
    ushort* Vl = W + 36 * M1;           // ends at 40M ushorts = 80 MB

    split_all<<<2048, 256, 0, stream>>>(x, wq, wk, wv, wo, xh, xl, wh, wl);

    // fused QKV projection: A = [wq|wk|wv] (M=3072), B = x (N=4096)
    gemm2<0><<<dim3(24, 32), 256, 0, stream>>>(wh, wl, xh, xl, bq, bk, bv,
                                               Qh, Ql, Kh, Kl, Vh, Vl, nullptr);

    attn_k<<<512, 256, 0, stream>>>(Qh, Ql, Kh, Kl, Vh, Vl, mask, xh, xl);

    // O-projection: A = wo (offset 3M in arena), B = ctx (= xh/xl)
    gemm2<1><<<dim3(8, 32), 256, 0, stream>>>(wh + 3 * M1, wl + 3 * M1, xh, xl,
                                              bo, nullptr, nullptr,
                                              nullptr, nullptr, nullptr, nullptr,
                                              nullptr, nullptr, out);
}

// Round 4
// 443.844 us; speedup vs baseline: 1.0399x; 1.0399x over previous
//
#include <hip/hip_runtime.h>
#include <hip/hip_bf16.h>

#define SEQ 2048
#define DM  1024

typedef __attribute__((ext_vector_type(8)))  short frag8;   // 8 bf16 (4 VGPR) MFMA A/B
typedef __attribute__((ext_vector_type(4)))  float f32x4;   // 16x16 C/D
typedef __attribute__((ext_vector_type(16))) float f32x16;  // 32x32 C/D

// ---------- bf16 split helpers ----------
__device__ __forceinline__ ushort f2bf(float x) {            // RNE
    union { float f; unsigned u; } c; c.f = x;
    return (ushort)((c.u + 0x7FFFu + ((c.u >> 16) & 1u)) >> 16);
}
__device__ __forceinline__ float bf2f(ushort h) {
    union { unsigned u; float f; } c; c.u = ((unsigned)h) << 16;
    return c.f;
}
__device__ __forceinline__ void split2(float x, ushort& h, ushort& l) {  // RNE hi
    h = f2bf(x);
    l = f2bf(x - bf2f(h));
}
__device__ __forceinline__ void tsplit(float x, ushort& h, ushort& l) {  // trunc hi (cheap)
    union { float f; unsigned u; } c; c.f = x;
    h = (ushort)(c.u >> 16);
    union { unsigned u; float f; } m; m.u = c.u & 0xFFFF0000u;
    union { float f; unsigned u; } d; d.f = x - m.f;
    l = (ushort)(d.u >> 16);
}

// ---------- async global->LDS (16B per lane, per-lane global addr, uniform LDS base) ----------
__device__ __forceinline__ void gload16(const void* g, void* l) {
    __builtin_amdgcn_global_load_lds(
        (const __attribute__((address_space(1))) unsigned*)(uintptr_t)g,
        (__attribute__((address_space(3))) unsigned*)(uintptr_t)l, 16, 0, 0);
}

// ============================================================================
// split_all: fp32 -> bf16 hi/lo arenas. x (4M elems) -> xh/xl; wq|wk|wv|wo -> wh/wl.
// ============================================================================
__global__ __launch_bounds__(256)
void split_all(const float* __restrict__ x,  const float* __restrict__ wq,
               const float* __restrict__ wk, const float* __restrict__ wv,
               const float* __restrict__ wo,
               ushort* __restrict__ xh, ushort* __restrict__ xl,
               ushort* __restrict__ wh, ushort* __restrict__ wl)
{
    const int NX4 = (2 * SEQ * DM) / 4;     // 1,048,576 float4
    const int NW4 = (DM * DM) / 4;          //   262,144 float4 per weight
    const int total = NX4 + 4 * NW4;
    for (int i = blockIdx.x * 256 + threadIdx.x; i < total; i += gridDim.x * 256) {
        float4 v; ushort4 *dh, *dl;
        if (i < NX4) {
            v = ((const float4*)x)[i];
            dh = (ushort4*)xh + i; dl = (ushort4*)xl + i;
        } else {
            const int j = i - NX4;
            const int wi = j >> 18;                 // /NW4
            const int jo = j & (NW4 - 1);
            const float* ws_ = (wi == 0) ? wq : (wi == 1) ? wk : (wi == 2) ? wv : wo;
            v = ((const float4*)ws_)[jo];
            dh = (ushort4*)wh + j; dl = (ushort4*)wl + j;
        }
        ushort4 h, l;
        split2(v.x, h.x, l.x); split2(v.y, h.y, l.y);
        split2(v.z, h.z, l.z); split2(v.w, h.w, l.w);
        *dh = h; *dl = l;
    }
}

// ============================================================================
// GEMM v3 (m97-faithful): C = A * B^T (+bias). Tile 128x128, 4 waves (2x2),
// BK=32 hi/lo, SINGLE-buffered 32 KB LDS, global_load_lds staging,
// stage -> barrier -> compute -> barrier.  Term-major MFMA interleave.
// Flat 1D grid, bijective XCD swizzle, m-fastest (consecutive blocks share
// the B (=x) panel within an XCD's private L2).
// LDS row: 8 chunks of 8 ushorts; logical c: 0..3 = hi k-chunk, 4..7 = lo.
// physical chunk p = c ^ (r&7)  (same involution on write-source and read).
// MODE 0: fused QKV (M=3072; m0>>10 selects Q/K/V epilogue)
// MODE 1: O-proj -> fp32 out
// ============================================================================
template<int MODE>
__global__ __launch_bounds__(256)
void gemm3(const ushort* __restrict__ Ah, const ushort* __restrict__ Al,
           const ushort* __restrict__ Bh, const ushort* __restrict__ Bl,
           const float* __restrict__ b0, const float* __restrict__ b1,
           const float* __restrict__ b2,
           ushort* __restrict__ Qh, ushort* __restrict__ Ql,
           ushort* __restrict__ Kh, ushort* __restrict__ Kl,
           ushort* __restrict__ Vh, ushort* __restrict__ Vl,
           float* __restrict__ outf, int nmt)
{
    __shared__ ushort As[128 * 64];
    __shared__ ushort Bs[128 * 64];

    const int t = threadIdx.x, w = t >> 6, lane = t & 63;

    // bijective XCD swizzle (nwg % 8 == 0 guaranteed by launch)
    const int nwg = gridDim.x;
    const int q8 = nwg >> 3;
    const int wg = (blockIdx.x & 7) * q8 + (blockIdx.x >> 3);
    const int m0 = (wg % nmt) * 128;
    const int n0 = (wg / nmt) * 128;

    const int wm = (w >> 1) * 64, wn = (w & 1) * 64;

    auto stage = [&](int k0) {
#pragma unroll
        for (int i = 0; i < 8; ++i) {
            const int gi = w * 8 + i;                    // 0..31: 0-15 A, 16-31 B
            const int rt = (gi & 15) * 8 + (lane >> 3);  // row in tile
            const int c  = (lane & 7) ^ (rt & 7);        // logical chunk at this slot
            const bool isA = gi < 16;
            const ushort* src = isA ? (c < 4 ? Ah : Al) : (c < 4 ? Bh : Bl);
            const size_t go = (size_t)((isA ? m0 : n0) + rt) * DM + k0 + (c & 3) * 8;
            ushort* dst = (isA ? As : Bs) + (gi & 15) * 512;
            gload16(src + go, dst);
        }
    };

    f32x16 acc[2][2];
#pragma unroll
    for (int i = 0; i < 2; ++i)
#pragma unroll
        for (int j = 0; j < 2; ++j)
#pragma unroll
            for (int r = 0; r < 16; ++r) acc[i][j][r] = 0.f;

    for (int ks = 0; ks < 32; ++ks) {
        __syncthreads();              // previous compute done reading LDS
        stage(ks * 32);
        __syncthreads();              // drains vmcnt(0): tile resident

#pragma unroll
        for (int kq = 0; kq < 2; ++kq) {
            frag8 a[2][2], b[2][2];   // [mi/ni][hi|lo]
#pragma unroll
            for (int mi = 0; mi < 2; ++mi) {
                const int r = wm + mi * 32 + (lane & 31);
                const int c = kq * 2 + (lane >> 5);
                a[mi][0] = *(const frag8*)&As[r * 64 + ((c       ^ (r & 7)) << 3)];
                a[mi][1] = *(const frag8*)&As[r * 64 + (((c + 4) ^ (r & 7)) << 3)];
            }
#pragma unroll
            for (int ni = 0; ni < 2; ++ni) {
                const int r = wn + ni * 32 + (lane & 31);
                const int c = kq * 2 + (lane >> 5);
                b[ni][0] = *(const frag8*)&Bs[r * 64 + ((c       ^ (r & 7)) << 3)];
                b[ni][1] = *(const frag8*)&Bs[r * 64 + (((c + 4) ^ (r & 7)) << 3)];
            }
            // term-major: 4 independent acc chains between same-acc reuse
            acc[0][0] = __builtin_amdgcn_mfma_f32_32x32x16_bf16(a[0][0], b[0][0], acc[0][0], 0, 0, 0);
            acc[0][1] = __builtin_amdgcn_mfma_f32_32x32x16_bf16(a[0][0], b[1][0], acc[0][1], 0, 0, 0);
            acc[1][0] = __builtin_amdgcn_mfma_f32_32x32x16_bf16(a[1][0], b[0][0], acc[1][0], 0, 0, 0);
            acc[1][1] = __builtin_amdgcn_mfma_f32_32x32x16_bf16(a[1][0], b[1][0], acc[1][1], 0, 0, 0);

            acc[0][0] = __builtin_amdgcn_mfma_f32_32x32x16_bf16(a[0][0], b[0][1], acc[0][0], 0, 0, 0);
            acc[0][1] = __builtin_amdgcn_mfma_f32_32x32x16_bf16(a[0][0], b[1][1], acc[0][1], 0, 0, 0);
            acc[1][0] = __builtin_amdgcn_mfma_f32_32x32x16_bf16(a[1][0], b[0][1], acc[1][0], 0, 0, 0);
            acc[1][1] = __builtin_amdgcn_mfma_f32_32x32x16_bf16(a[1][0], b[1][1], acc[1][1], 0, 0, 0);

            acc[0][0] = __builtin_amdgcn_mfma_f32_32x32x16_bf16(a[0][1], b[0][0], acc[0][0], 0, 0, 0);
            acc[0][1] = __builtin_amdgcn_mfma_f32_32x32x16_bf16(a[0][1], b[1][0], acc[0][1], 0, 0, 0);
            acc[1][0] = __builtin_amdgcn_mfma_f32_32x32x16_bf16(a[1][1], b[0][0], acc[1][0], 0, 0, 0);
            acc[1][1] = __builtin_amdgcn_mfma_f32_32x32x16_bf16(a[1][1], b[1][0], acc[1][1], 0, 0, 0);
        }
    }

    // ---- epilogue: C row m = (reg&3)+8*(reg>>2)+4*(lane>>5), col n = lane&31 ----
    const int g = lane >> 5;
    const int mode = m0 >> 10;   // 0=Q 1=K 2=V (MODE 0 only)
#pragma unroll
    for (int mi = 0; mi < 2; ++mi)
#pragma unroll
        for (int ni = 0; ni < 2; ++ni) {
            const int col = n0 + wn + ni * 32 + (lane & 31);
            const int b = col >> 11, s = col & 2047;
            f32x16 v = acc[mi][ni];
#pragma unroll
            for (int q2 = 0; q2 < 4; ++q2) {
                const int row = m0 + wm + mi * 32 + q2 * 8 + g * 4;   // 4 consecutive
                if (MODE == 1) {
                    float4 o;
                    o.x = v[q2 * 4 + 0] + b0[row + 0];
                    o.y = v[q2 * 4 + 1] + b0[row + 1];
                    o.z = v[q2 * 4 + 2] + b0[row + 2];
                    o.w = v[q2 * 4 + 3] + b0[row + 3];
                    *(float4*)&outf[(size_t)col * DM + row] = o;
                } else {
                    const int e = row & 1023;
                    const int h = e >> 6, dk = e & 63;
                    const float* bp = (mode == 0) ? b0 : (mode == 1) ? b1 : b2;
                    const float sc = (mode == 0) ? 0.125f : 1.0f;
                    float v0 = (v[q2 * 4 + 0] + bp[e + 0]) * sc;
                    float v1 = (v[q2 * 4 + 1] + bp[e + 1]) * sc;
                    float v2 = (v[q2 * 4 + 2] + bp[e + 2]) * sc;
                    float v3 = (v[q2 * 4 + 3] + bp[e + 3]) * sc;
                    ushort4 hi, lo;
                    split2(v0, hi.x, lo.x); split2(v1, hi.y, lo.y);
                    split2(v2, hi.z, lo.z); split2(v3, hi.w, lo.w);
                    const int bh = b * 16 + h;
                    if (mode == 0) {
                        const size_t off = ((size_t)bh * SEQ + s) * 64 + dk;
                        *(ushort4*)&Qh[off] = hi; *(ushort4*)&Ql[off] = lo;
                    } else if (mode == 1) {
                        const size_t off = ((size_t)bh * SEQ + s) * 64 + dk;
                        *(ushort4*)&Kh[off] = hi; *(ushort4*)&Kl[off] = lo;
                    } else {   // V transposed: [bh][dk][s]
                        const size_t o0 = ((size_t)bh * 64 + dk) * SEQ + s;
                        Vh[o0]            = hi.x; Vl[o0]            = lo.x;
                        Vh[o0 + SEQ]      = hi.y; Vl[o0 + SEQ]      = lo.y;
                        Vh[o0 + 2 * SEQ]  = hi.z; Vl[o0 + 2 * SEQ]  = lo.z;
                        Vh[o0 + 3 * SEQ]  = hi.w; Vl[o0 + 3 * SEQ]  = lo.w;
                    }
                }
            }
        }
}

// ============================================================================
// Flash attention, bf16x3, swapped QK^T; T14 async-stage; trunc P-split.
// Block = (b,h,qtile 128); 4 waves x 32 q. Writes ctx as bf16 hi/lo.
// (unchanged from R3)
// ============================================================================
__global__ __launch_bounds__(256, 2)
void attn_k(const ushort* __restrict__ Qh, const ushort* __restrict__ Ql,
            const ushort* __restrict__ Kh, const ushort* __restrict__ Kl,
            const ushort* __restrict__ Vh, const ushort* __restrict__ Vl,
            const int* __restrict__ mask,
            ushort* __restrict__ ch, ushort* __restrict__ cl)
{
    __shared__ ushort Ks[64 * 128];     // [key][16 chunks: hi 0..7 | lo 8..15] over dk
    __shared__ ushort Vs[64 * 128];     // [d][16 chunks] over keys
    __shared__ ushort Ps[4][32 * 128];  // per-wave P^T [q][16 chunks] over keys

    const int t = threadIdx.x, w = t >> 6, lane = t & 63;
    const int bh = blockIdx.x >> 4, qt = blockIdx.x & 15;
    const int b = bh >> 4, h = bh & 15;
    const int q0 = qt * 128 + w * 32;
    const size_t base = (size_t)bh * SEQ * 64;

    // Q fragments (B-operand): col q = lane&15, 8 contiguous dk
    frag8 qfh[2][2], qfl[2][2];
#pragma unroll
    for (int nf = 0; nf < 2; ++nf)
#pragma unroll
        for (int kb = 0; kb < 2; ++kb) {
            const size_t off = base + (size_t)(q0 + nf * 16 + (lane & 15)) * 64
                             + kb * 32 + ((lane >> 4) << 3);
            qfh[nf][kb] = *(const frag8*)&Qh[off];
            qfl[nf][kb] = *(const frag8*)&Ql[off];
        }

    int msk[2];
#pragma unroll
    for (int nf = 0; nf < 2; ++nf)
        msk[nf] = mask[b * SEQ + q0 + nf * 16 + (lane & 15)];

    float m_run[2] = {-1e30f, -1e30f}, l_run[2] = {0.f, 0.f};
    f32x4 acc[4][2];
#pragma unroll
    for (int df = 0; df < 4; ++df)
#pragma unroll
        for (int nf = 0; nf < 2; ++nf) acc[df][nf] = f32x4{0.f, 0.f, 0.f, 0.f};

    frag8 sK[4], sV[4];
    auto stage_load = [&](int kt) {
#pragma unroll
        for (int j = 0; j < 4; ++j) {
            const int i = j * 256 + t, r = i >> 4, cc = i & 15, cli = cc & 7;
            const ushort* kp = (cc < 8) ? Kh : Kl;
            const ushort* vp = (cc < 8) ? Vh : Vl;
            sK[j] = *(const frag8*)&kp[base + (size_t)(kt * 64 + r) * 64 + (cli << 3)];
            sV[j] = *(const frag8*)&vp[base + (size_t)r * SEQ + kt * 64 + (cli << 3)];
        }
    };
    auto stage_write = [&]() {
#pragma unroll
        for (int j = 0; j < 4; ++j) {
            const int i = j * 256 + t, r = i >> 4, cc = i & 15, cli = cc & 7;
            const int ph = (cli ^ (r & 7)) + (cc & 8);
            *(frag8*)&Ks[r * 128 + (ph << 3)] = sK[j];
            *(frag8*)&Vs[r * 128 + (ph << 3)] = sV[j];
        }
    };

    stage_load(0); stage_write();
    __syncthreads();

    for (int kt = 0; kt < SEQ / 64; ++kt) {
        if (kt < SEQ / 64 - 1) stage_load(kt + 1);   // T14: issue early

        // ---- S^T = K * Q^T ----
        f32x4 st[4][2];
#pragma unroll
        for (int mf = 0; mf < 4; ++mf)
#pragma unroll
            for (int nf = 0; nf < 2; ++nf) st[mf][nf] = f32x4{0.f, 0.f, 0.f, 0.f};
#pragma unroll
        for (int mf = 0; mf < 4; ++mf) {
            const int r = mf * 16 + (lane & 15);
            const int cb = lane >> 4;
#pragma unroll
            for (int kb = 0; kb < 2; ++kb) {
                const int c = kb * 4 + cb;
                const int p = c ^ (r & 7);
                frag8 kfh = *(const frag8*)&Ks[r * 128 + (p << 3)];
                frag8 kfl = *(const frag8*)&Ks[r * 128 + ((p + 8) << 3)];
#pragma unroll
                for (int nf = 0; nf < 2; ++nf) {
                    st[mf][nf] = __builtin_amdgcn_mfma_f32_16x16x32_bf16(kfh, qfh[nf][kb], st[mf][nf], 0, 0, 0);
                    st[mf][nf] = __builtin_amdgcn_mfma_f32_16x16x32_bf16(kfh, qfl[nf][kb], st[mf][nf], 0, 0, 0);
                    st[mf][nf] = __builtin_amdgcn_mfma_f32_16x16x32_bf16(kfl, qfh[nf][kb], st[mf][nf], 0, 0, 0);
                }
            }
        }

        // ---- online softmax over keys (per q-column) ----
        float corr[2];
#pragma unroll
        for (int nf = 0; nf < 2; ++nf) {
            if (msk[nf] == 0) {
#pragma unroll
                for (int mf = 0; mf < 4; ++mf) st[mf][nf] = f32x4{0.f, 0.f, 0.f, 0.f};
            }
            float mx = -1e30f;
#pragma unroll
            for (int mf = 0; mf < 4; ++mf)
#pragma unroll
                for (int r4 = 0; r4 < 4; ++r4) mx = fmaxf(mx, st[mf][nf][r4]);
            mx = fmaxf(mx, __shfl_xor(mx, 16));
            mx = fmaxf(mx, __shfl_xor(mx, 32));
            const float mnew = fmaxf(m_run[nf], mx);
            corr[nf] = __expf(m_run[nf] - mnew);
            m_run[nf] = mnew;
            float ss = 0.f;
#pragma unroll
            for (int mf = 0; mf < 4; ++mf)
#pragma unroll
                for (int r4 = 0; r4 < 4; ++r4) {
                    const float p = __expf(st[mf][nf][r4] - mnew);
                    st[mf][nf][r4] = p; ss += p;
                }
            ss += __shfl_xor(ss, 16);
            ss += __shfl_xor(ss, 32);
            l_run[nf] = l_run[nf] * corr[nf] + ss;
#pragma unroll
            for (int df = 0; df < 4; ++df)
#pragma unroll
                for (int r4 = 0; r4 < 4; ++r4) acc[df][nf][r4] *= corr[nf];
        }

        // ---- P^T -> per-wave LDS (truncation split) ----
#pragma unroll
        for (int nf = 0; nf < 2; ++nf) {
            const int q = nf * 16 + (lane & 15);
#pragma unroll
            for (int mf = 0; mf < 4; ++mf) {
                const int key0 = mf * 16 + ((lane >> 4) << 2);
                ushort4 hi, lo;
                tsplit(st[mf][nf][0], hi.x, lo.x);
                tsplit(st[mf][nf][1], hi.y, lo.y);
                tsplit(st[mf][nf][2], hi.z, lo.z);
                tsplit(st[mf][nf][3], hi.w, lo.w);
                const int c = key0 >> 3, sub = key0 & 7;
                const int p = c ^ (q & 7);
                *(ushort4*)&Ps[w][q * 128 + (p << 3) + sub] = hi;
                *(ushort4*)&Ps[w][q * 128 + ((p + 8) << 3) + sub] = lo;
            }
        }

        // ---- ctx^T += V^T * P^T ----
        frag8 pfh[2][2], pfl[2][2];
#pragma unroll
        for (int nf = 0; nf < 2; ++nf) {
            const int q = nf * 16 + (lane & 15);
            const int cb = lane >> 4;
#pragma unroll
            for (int kb = 0; kb < 2; ++kb) {
                const int c = kb * 4 + cb;
                const int p = c ^ (q & 7);
                pfh[nf][kb] = *(const frag8*)&Ps[w][q * 128 + (p << 3)];
                pfl[nf][kb] = *(const frag8*)&Ps[w][q * 128 + ((p + 8) << 3)];
            }
        }
#pragma unroll
        for (int df = 0; df < 4; ++df) {
            const int r = df * 16 + (lane & 15);
            const int cb = lane >> 4;
#pragma unroll
            for (int kb = 0; kb < 2; ++kb) {
                const int c = kb * 4 + cb;
                const int p = c ^ (r & 7);
                frag8 vfh = *(const frag8*)&Vs[r * 128 + (p << 3)];
                frag8 vfl = *(const frag8*)&Vs[r * 128 + ((p + 8) << 3)];
#pragma unroll
                for (int nf = 0; nf < 2; ++nf) {
                    acc[df][nf] = __builtin_amdgcn_mfma_f32_16x16x32_bf16(vfh, pfh[nf][kb], acc[df][nf], 0, 0, 0);
                    acc[df][nf] = __builtin_amdgcn_mfma_f32_16x16x32_bf16(vfh, pfl[nf][kb], acc[df][nf], 0, 0, 0);
                    acc[df][nf] = __builtin_amdgcn_mfma_f32_16x16x32_bf16(vfl, pfh[nf][kb], acc[df][nf], 0, 0, 0);
                }
            }
        }

        __syncthreads();                          // all reads of Ks/Vs done
        if (kt < SEQ / 64 - 1) {
            stage_write();                        // T14: write late
            __syncthreads();
        }
    }

    // ---- epilogue: ctx as bf16 hi/lo, [b][s][h*64+d] ----
#pragma unroll
    for (int nf = 0; nf < 2; ++nf) {
        const float inv = 1.0f / l_run[nf];
        const int s = q0 + nf * 16 + (lane & 15);
#pragma unroll
        for (int df = 0; df < 4; ++df) {
            const int e0 = h * 64 + df * 16 + ((lane >> 4) << 2);
            ushort4 hi, lo;
            split2(acc[df][nf][0] * inv, hi.x, lo.x);
            split2(acc[df][nf][1] * inv, hi.y, lo.y);
            split2(acc[df][nf][2] * inv, hi.z, lo.z);
            split2(acc[df][nf][3] * inv, hi.w, lo.w);
            const size_t off = (size_t)(b * SEQ + s) * DM + e0;
            *(ushort4*)&ch[off] = hi;
            *(ushort4*)&cl[off] = lo;
        }
    }
}

extern "C" void kernel_launch(void* const* d_in, const int* in_sizes, int n_in,
                              void* d_out, int out_size, void* d_ws, size_t ws_size,
                              hipStream_t stream)
{
    const float* x  = (const float*)d_in[0];
    const int* mask = (const int*)d_in[1];
    const float* wq = (const float*)d_in[2];
    const float* bq = (const float*)d_in[3];
    const float* wk = (const float*)d_in[4];
    const float* bk = (const float*)d_in[5];
    const float* wv = (const float*)d_in[6];
    const float* bv = (const float*)d_in[7];
    const float* wo = (const float*)d_in[8];
    const float* bo = (const float*)d_in[9];
    float* out = (float*)d_out;

    const size_t M1 = 1024 * 1024;      // 1M elements
    ushort* W = (ushort*)d_ws;          // 80 MB arena
    ushort* xh = W;                     // 4M  (doubles as ctx_hi after attn)
    ushort* xl = W + 4 * M1;            // 4M  (ctx_lo)
    ushort* wh = W + 8 * M1;            // 4M: wq|wk|wv|wo
    ushort* wl = W + 12 * M1;
    ushort* Qh = W + 16 * M1;
    ushort* Ql = W + 20 * M1;
    ushort* Kh = W + 24 * M1;
    ushort* Kl = W + 28 * M1;
    ushort* Vh = W + 32 * M1;
    ushort* Vl = W + 36 * M1;           // ends at 40M ushorts = 80 MB

    split_all<<<2048, 256, 0, stream>>>(x, wq, wk, wv, wo, xh, xl, wh, wl);

    // fused QKV projection: A = [wq|wk|wv] (M=3072, nmt=24), B = x (N=4096, nnt=32)
    gemm3<0><<<24 * 32, 256, 0, stream>>>(wh, wl, xh, xl, bq, bk, bv,
                                          Qh, Ql, Kh, Kl, Vh, Vl, nullptr, 24);

    attn_k<<<512, 256, 0, stream>>>(Qh, Ql, Kh, Kl, Vh, Vl, mask, xh, xl);

    // O-projection: A = wo (offset 3M in arena, nmt=8), B = ctx (= xh/xl)
    gemm3<1><<<8 * 32, 256, 0, stream>>>(wh + 3 * M1, wl + 3 * M1, xh, xl,
                                         bo, nullptr, nullptr,
                                         nullptr, nullptr, nullptr, nullptr,
                                         nullptr, nullptr, out, 8);
}

// Round 5
// 238.014 us; speedup vs baseline: 1.9392x; 1.8648x over previous
//
#include <hip/hip_runtime.h>
#include <hip/hip_bf16.h>

#define SEQ 2048
#define DM  1024

typedef __attribute__((ext_vector_type(8)))  short frag8;   // 8 bf16 (4 VGPR) MFMA A/B
typedef __attribute__((ext_vector_type(4)))  float f32x4;   // 16x16 C/D

// ---------- bf16 split helpers ----------
__device__ __forceinline__ ushort f2bf(float x) {            // RNE
    union { float f; unsigned u; } c; c.f = x;
    return (ushort)((c.u + 0x7FFFu + ((c.u >> 16) & 1u)) >> 16);
}
__device__ __forceinline__ float bf2f(ushort h) {
    union { unsigned u; float f; } c; c.u = ((unsigned)h) << 16;
    return c.f;
}
__device__ __forceinline__ void split2(float x, ushort& h, ushort& l) {  // RNE hi
    h = f2bf(x);
    l = f2bf(x - bf2f(h));
}
__device__ __forceinline__ void tsplit(float x, ushort& h, ushort& l) {  // trunc hi (cheap)
    union { float f; unsigned u; } c; c.f = x;
    h = (ushort)(c.u >> 16);
    union { unsigned u; float f; } m; m.u = c.u & 0xFFFF0000u;
    union { float f; unsigned u; } d; d.f = x - m.f;
    l = (ushort)(d.u >> 16);
}

// ---------- async global->LDS (16B/lane, per-lane global addr, wave-uniform LDS base) ----------
__device__ __forceinline__ void gload16(const void* g, void* l) {
    __builtin_amdgcn_global_load_lds(
        (const __attribute__((address_space(1))) unsigned*)(uintptr_t)g,
        (__attribute__((address_space(3))) unsigned*)(uintptr_t)l, 16, 0, 0);
}

// ============================================================================
// split_all: fp32 -> bf16 hi/lo arenas. x (4M elems) -> xh/xl; wq|wk|wv|wo -> wh/wl.
// ============================================================================
__global__ __launch_bounds__(256)
void split_all(const float* __restrict__ x,  const float* __restrict__ wq,
               const float* __restrict__ wk, const float* __restrict__ wv,
               const float* __restrict__ wo,
               ushort* __restrict__ xh, ushort* __restrict__ xl,
               ushort* __restrict__ wh, ushort* __restrict__ wl)
{
    const int NX4 = (2 * SEQ * DM) / 4;     // 1,048,576 float4
    const int NW4 = (DM * DM) / 4;          //   262,144 float4 per weight
    const int total = NX4 + 4 * NW4;
    for (int i = blockIdx.x * 256 + threadIdx.x; i < total; i += gridDim.x * 256) {
        float4 v; ushort4 *dh, *dl;
        if (i < NX4) {
            v = ((const float4*)x)[i];
            dh = (ushort4*)xh + i; dl = (ushort4*)xl + i;
        } else {
            const int j = i - NX4;
            const int wi = j >> 18;                 // /NW4
            const int jo = j & (NW4 - 1);
            const float* ws_ = (wi == 0) ? wq : (wi == 1) ? wk : (wi == 2) ? wv : wo;
            v = ((const float4*)ws_)[jo];
            dh = (ushort4*)wh + j; dl = (ushort4*)wl + j;
        }
        ushort4 h, l;
        split2(v.x, h.x, l.x); split2(v.y, h.y, l.y);
        split2(v.z, h.z, l.z); split2(v.w, h.w, l.w);
        *dh = h; *dl = l;
    }
}

// ============================================================================
// GEMM v4: counted-vmcnt pipelined (T3+T4+T5).  C = A * B^T (+bias).
// A rows m (contig k), B rows n (contig k), pre-split bf16 hi/lo.
// K-tile = 32 k (row = 64 ushorts: chunks 0..3 hi, 4..7 lo, 16B each,
// physical chunk = logical ^ (row&7) -- conflict-free for frag reads,
// DMA-linear dest with inverse-swizzled global source).
// Ping-pong K-tile buffers; prologue stages tiles 0,1; iter t computes
// tile t, waits vmcnt(NL) (tile t landed, t+1 in flight), raw barriers,
// issues tile t+2 at iter end.  B-fragments register-cached per iter.
// MODE 0: fused QKV (sel = row>>10 picks Q/K/V epilogue)
// MODE 1: O-proj -> fp32 out
// ============================================================================
template<int BM, int BN, int WM, int WN, int MODE>
__global__ __launch_bounds__(WM * WN * 64)
void gemm4(const ushort* __restrict__ Ah, const ushort* __restrict__ Al,
           const ushort* __restrict__ Bh, const ushort* __restrict__ Bl,
           const float* __restrict__ b0, const float* __restrict__ b1,
           const float* __restrict__ b2,
           ushort* __restrict__ Qh, ushort* __restrict__ Ql,
           ushort* __restrict__ Kh, ushort* __restrict__ Kl,
           ushort* __restrict__ Vh, ushort* __restrict__ Vl,
           float* __restrict__ outf, int nmt)
{
    constexpr int NW  = WM * WN;
    constexpr int PR  = BM / WM, PC = BN / WN;
    constexpr int MR  = PR / 16, NR = PC / 16, MH = MR / 2;
    constexpr int APW = (BM / 8) / NW;          // A 1KB-slices per wave
    constexpr int BPW = (BN / 8) / NW;          // B 1KB-slices per wave
    constexpr int NL  = APW + BPW;              // gloads/wave/K-tile
    constexpr int NT  = DM / 32;                // 32 K-tiles

    __shared__ ushort A_lds[2][BM * 64];
    __shared__ ushort B_lds[2][BN * 64];

    const int tid = threadIdx.x, w = tid >> 6, lane = tid & 63;
    const int nwg = gridDim.x, q8 = nwg >> 3;   // grid % 8 == 0 (bijective XCD swizzle)
    const int wg  = (blockIdx.x & 7) * q8 + (blockIdx.x >> 3);
    const int m0  = (wg % nmt) * BM, n0 = (wg / nmt) * BN;
    const int wm  = w / WN, wn = w % WN;

    auto stage = [&](int buf, int kt) {
        const int k0 = kt * 32;
#pragma unroll
        for (int j = 0; j < APW; ++j) {
            const int s   = w * APW + j;
            const int row = s * 8 + (lane >> 3);
            const int cl  = (lane & 7) ^ (lane >> 3);    // inverse-swizzled logical chunk
            const ushort* src = (cl < 4) ? Ah : Al;
            gload16(src + (size_t)(m0 + row) * DM + k0 + (cl & 3) * 8,
                    &A_lds[buf][s * 512]);
        }
#pragma unroll
        for (int j = 0; j < BPW; ++j) {
            const int s   = w * BPW + j;
            const int row = s * 8 + (lane >> 3);
            const int cl  = (lane & 7) ^ (lane >> 3);
            const ushort* src = (cl < 4) ? Bh : Bl;
            gload16(src + (size_t)(n0 + row) * DM + k0 + (cl & 3) * 8,
                    &B_lds[buf][s * 512]);
        }
    };

    f32x4 acc[MR][NR];
#pragma unroll
    for (int i = 0; i < MR; ++i)
#pragma unroll
        for (int j = 0; j < NR; ++j) acc[i][j] = f32x4{0.f, 0.f, 0.f, 0.f};

    stage(0, 0);
    stage(1, 1);

    for (int t = 0; t < NT; ++t) {
        const int buf = t & 1;
        if (t == NT - 1) {
            asm volatile("s_waitcnt vmcnt(0)" ::: "memory");
        } else {
            if constexpr (NL == 7)      asm volatile("s_waitcnt vmcnt(7)" ::: "memory");
            else if constexpr (NL == 8) asm volatile("s_waitcnt vmcnt(8)" ::: "memory");
            else                        asm volatile("s_waitcnt vmcnt(0)" ::: "memory");
        }
        __builtin_amdgcn_sched_barrier(0);
        __builtin_amdgcn_s_barrier();

        // B fragments: read once per iter, cached in regs
        frag8 bh_[NR], bl_[NR];
#pragma unroll
        for (int nf = 0; nf < NR; ++nf) {
            const int r = wn * PC + nf * 16 + (lane & 15);
            const int c = lane >> 4;
            bh_[nf] = *(const frag8*)&B_lds[buf][r * 64 + ((c       ^ (r & 7)) << 3)];
            bl_[nf] = *(const frag8*)&B_lds[buf][r * 64 + (((c + 4) ^ (r & 7)) << 3)];
        }
#pragma unroll
        for (int qm = 0; qm < 2; ++qm) {
            frag8 ah_[MH], al_[MH];
#pragma unroll
            for (int mf = 0; mf < MH; ++mf) {
                const int r = wm * PR + qm * (PR / 2) + mf * 16 + (lane & 15);
                const int c = lane >> 4;
                ah_[mf] = *(const frag8*)&A_lds[buf][r * 64 + ((c       ^ (r & 7)) << 3)];
                al_[mf] = *(const frag8*)&A_lds[buf][r * 64 + (((c + 4) ^ (r & 7)) << 3)];
            }
            __builtin_amdgcn_s_setprio(1);
#pragma unroll
            for (int mf = 0; mf < MH; ++mf)
#pragma unroll
                for (int nf = 0; nf < NR; ++nf) {
                    acc[qm * MH + mf][nf] = __builtin_amdgcn_mfma_f32_16x16x32_bf16(
                        ah_[mf], bh_[nf], acc[qm * MH + mf][nf], 0, 0, 0);
                    acc[qm * MH + mf][nf] = __builtin_amdgcn_mfma_f32_16x16x32_bf16(
                        ah_[mf], bl_[nf], acc[qm * MH + mf][nf], 0, 0, 0);
                    acc[qm * MH + mf][nf] = __builtin_amdgcn_mfma_f32_16x16x32_bf16(
                        al_[mf], bh_[nf], acc[qm * MH + mf][nf], 0, 0, 0);
                }
            __builtin_amdgcn_s_setprio(0);
        }
        __builtin_amdgcn_sched_barrier(0);
        __builtin_amdgcn_s_barrier();
        __builtin_amdgcn_sched_barrier(0);
        if (t + 2 < NT) stage(buf, t + 2);      // into just-freed buffer
    }

    // ---- epilogue: C row m = mf*16 + (lane>>4)*4 + reg (4 consec), col n = lane&15 ----
#pragma unroll
    for (int mf = 0; mf < MR; ++mf)
#pragma unroll
        for (int nf = 0; nf < NR; ++nf) {
            const int col  = n0 + wn * PC + nf * 16 + (lane & 15);
            const int row0 = m0 + wm * PR + mf * 16 + ((lane >> 4) << 2);
            f32x4 v = acc[mf][nf];
            if constexpr (MODE == 1) {
                float4 o;
                o.x = v[0] + b0[row0 + 0];
                o.y = v[1] + b0[row0 + 1];
                o.z = v[2] + b0[row0 + 2];
                o.w = v[3] + b0[row0 + 3];
                *(float4*)&outf[(size_t)col * DM + row0] = o;
            } else {
                const int sel = row0 >> 10;          // 0=Q 1=K 2=V
                const int e = row0 & 1023;
                const int b = col >> 11, s = col & 2047;
                const int h = e >> 6, dk = e & 63;
                const float* bp = (sel == 0) ? b0 : (sel == 1) ? b1 : b2;
                const float sc = (sel == 0) ? 0.125f : 1.0f;
                float v0 = (v[0] + bp[e + 0]) * sc;
                float v1 = (v[1] + bp[e + 1]) * sc;
                float v2 = (v[2] + bp[e + 2]) * sc;
                float v3 = (v[3] + bp[e + 3]) * sc;
                ushort4 hi, lo;
                split2(v0, hi.x, lo.x); split2(v1, hi.y, lo.y);
                split2(v2, hi.z, lo.z); split2(v3, hi.w, lo.w);
                const int bh = b * 16 + h;
                if (sel == 0) {
                    const size_t off = ((size_t)bh * SEQ + s) * 64 + dk;
                    *(ushort4*)&Qh[off] = hi; *(ushort4*)&Ql[off] = lo;
                } else if (sel == 1) {
                    const size_t off = ((size_t)bh * SEQ + s) * 64 + dk;
                    *(ushort4*)&Kh[off] = hi; *(ushort4*)&Kl[off] = lo;
                } else {   // V transposed: [bh][dk][s]
                    const size_t o0 = ((size_t)bh * 64 + dk) * SEQ + s;
                    Vh[o0]           = hi.x; Vl[o0]           = lo.x;
                    Vh[o0 + SEQ]     = hi.y; Vl[o0 + SEQ]     = lo.y;
                    Vh[o0 + 2 * SEQ] = hi.z; Vl[o0 + 2 * SEQ] = lo.z;
                    Vh[o0 + 3 * SEQ] = hi.w; Vl[o0 + 3 * SEQ] = lo.w;
                }
            }
        }
}

// ============================================================================
// Flash attention, bf16x3, swapped QK^T; T14 async-stage; trunc P-split.
// Block = (b,h,qtile 128); 4 waves x 32 q. Writes ctx as bf16 hi/lo.
// (R3/R4 kernel + T5 setprio around MFMA clusters)
// ============================================================================
__global__ __launch_bounds__(256, 2)
void attn_k(const ushort* __restrict__ Qh, const ushort* __restrict__ Ql,
            const ushort* __restrict__ Kh, const ushort* __restrict__ Kl,
            const ushort* __restrict__ Vh, const ushort* __restrict__ Vl,
            const int* __restrict__ mask,
            ushort* __restrict__ ch, ushort* __restrict__ cl)
{
    __shared__ ushort Ks[64 * 128];     // [key][16 chunks: hi 0..7 | lo 8..15] over dk
    __shared__ ushort Vs[64 * 128];     // [d][16 chunks] over keys
    __shared__ ushort Ps[4][32 * 128];  // per-wave P^T [q][16 chunks] over keys

    const int t = threadIdx.x, w = t >> 6, lane = t & 63;
    const int bh = blockIdx.x >> 4, qt = blockIdx.x & 15;
    const int b = bh >> 4, h = bh & 15;
    const int q0 = qt * 128 + w * 32;
    const size_t base = (size_t)bh * SEQ * 64;

    // Q fragments (B-operand): col q = lane&15, 8 contiguous dk
    frag8 qfh[2][2], qfl[2][2];
#pragma unroll
    for (int nf = 0; nf < 2; ++nf)
#pragma unroll
        for (int kb = 0; kb < 2; ++kb) {
            const size_t off = base + (size_t)(q0 + nf * 16 + (lane & 15)) * 64
                             + kb * 32 + ((lane >> 4) << 3);
            qfh[nf][kb] = *(const frag8*)&Qh[off];
            qfl[nf][kb] = *(const frag8*)&Ql[off];
        }

    int msk[2];
#pragma unroll
    for (int nf = 0; nf < 2; ++nf)
        msk[nf] = mask[b * SEQ + q0 + nf * 16 + (lane & 15)];

    float m_run[2] = {-1e30f, -1e30f}, l_run[2] = {0.f, 0.f};
    f32x4 acc[4][2];
#pragma unroll
    for (int df = 0; df < 4; ++df)
#pragma unroll
        for (int nf = 0; nf < 2; ++nf) acc[df][nf] = f32x4{0.f, 0.f, 0.f, 0.f};

    frag8 sK[4], sV[4];
    auto stage_load = [&](int kt) {
#pragma unroll
        for (int j = 0; j < 4; ++j) {
            const int i = j * 256 + t, r = i >> 4, cc = i & 15, cli = cc & 7;
            const ushort* kp = (cc < 8) ? Kh : Kl;
            const ushort* vp = (cc < 8) ? Vh : Vl;
            sK[j] = *(const frag8*)&kp[base + (size_t)(kt * 64 + r) * 64 + (cli << 3)];
            sV[j] = *(const frag8*)&vp[base + (size_t)r * SEQ + kt * 64 + (cli << 3)];
        }
    };
    auto stage_write = [&]() {
#pragma unroll
        for (int j = 0; j < 4; ++j) {
            const int i = j * 256 + t, r = i >> 4, cc = i & 15, cli = cc & 7;
            const int ph = (cli ^ (r & 7)) + (cc & 8);
            *(frag8*)&Ks[r * 128 + (ph << 3)] = sK[j];
            *(frag8*)&Vs[r * 128 + (ph << 3)] = sV[j];
        }
    };

    stage_load(0); stage_write();
    __syncthreads();

    for (int kt = 0; kt < SEQ / 64; ++kt) {
        if (kt < SEQ / 64 - 1) stage_load(kt + 1);   // T14: issue early

        // ---- S^T = K * Q^T ----
        f32x4 st[4][2];
#pragma unroll
        for (int mf = 0; mf < 4; ++mf)
#pragma unroll
            for (int nf = 0; nf < 2; ++nf) st[mf][nf] = f32x4{0.f, 0.f, 0.f, 0.f};
        __builtin_amdgcn_s_setprio(1);
#pragma unroll
        for (int mf = 0; mf < 4; ++mf) {
            const int r = mf * 16 + (lane & 15);
            const int cb = lane >> 4;
#pragma unroll
            for (int kb = 0; kb < 2; ++kb) {
                const int c = kb * 4 + cb;
                const int p = c ^ (r & 7);
                frag8 kfh = *(const frag8*)&Ks[r * 128 + (p << 3)];
                frag8 kfl = *(const frag8*)&Ks[r * 128 + ((p + 8) << 3)];
#pragma unroll
                for (int nf = 0; nf < 2; ++nf) {
                    st[mf][nf] = __builtin_amdgcn_mfma_f32_16x16x32_bf16(kfh, qfh[nf][kb], st[mf][nf], 0, 0, 0);
                    st[mf][nf] = __builtin_amdgcn_mfma_f32_16x16x32_bf16(kfh, qfl[nf][kb], st[mf][nf], 0, 0, 0);
                    st[mf][nf] = __builtin_amdgcn_mfma_f32_16x16x32_bf16(kfl, qfh[nf][kb], st[mf][nf], 0, 0, 0);
                }
            }
        }
        __builtin_amdgcn_s_setprio(0);

        // ---- online softmax over keys (per q-column) ----
        float corr[2];
#pragma unroll
        for (int nf = 0; nf < 2; ++nf) {
            if (msk[nf] == 0) {
#pragma unroll
                for (int mf = 0; mf < 4; ++mf) st[mf][nf] = f32x4{0.f, 0.f, 0.f, 0.f};
            }
            float mx = -1e30f;
#pragma unroll
            for (int mf = 0; mf < 4; ++mf)
#pragma unroll
                for (int r4 = 0; r4 < 4; ++r4) mx = fmaxf(mx, st[mf][nf][r4]);
            mx = fmaxf(mx, __shfl_xor(mx, 16));
            mx = fmaxf(mx, __shfl_xor(mx, 32));
            const float mnew = fmaxf(m_run[nf], mx);
            corr[nf] = __expf(m_run[nf] - mnew);
            m_run[nf] = mnew;
            float ss = 0.f;
#pragma unroll
            for (int mf = 0; mf < 4; ++mf)
#pragma unroll
                for (int r4 = 0; r4 < 4; ++r4) {
                    const float p = __expf(st[mf][nf][r4] - mnew);
                    st[mf][nf][r4] = p; ss += p;
                }
            ss += __shfl_xor(ss, 16);
            ss += __shfl_xor(ss, 32);
            l_run[nf] = l_run[nf] * corr[nf] + ss;
#pragma unroll
            for (int df = 0; df < 4; ++df)
#pragma unroll
                for (int r4 = 0; r4 < 4; ++r4) acc[df][nf][r4] *= corr[nf];
        }

        // ---- P^T -> per-wave LDS (truncation split) ----
#pragma unroll
        for (int nf = 0; nf < 2; ++nf) {
            const int q = nf * 16 + (lane & 15);
#pragma unroll
            for (int mf = 0; mf < 4; ++mf) {
                const int key0 = mf * 16 + ((lane >> 4) << 2);
                ushort4 hi, lo;
                tsplit(st[mf][nf][0], hi.x, lo.x);
                tsplit(st[mf][nf][1], hi.y, lo.y);
                tsplit(st[mf][nf][2], hi.z, lo.z);
                tsplit(st[mf][nf][3], hi.w, lo.w);
                const int c = key0 >> 3, sub = key0 & 7;
                const int p = c ^ (q & 7);
                *(ushort4*)&Ps[w][q * 128 + (p << 3) + sub] = hi;
                *(ushort4*)&Ps[w][q * 128 + ((p + 8) << 3) + sub] = lo;
            }
        }

        // ---- ctx^T += V^T * P^T ----
        frag8 pfh[2][2], pfl[2][2];
#pragma unroll
        for (int nf = 0; nf < 2; ++nf) {
            const int q = nf * 16 + (lane & 15);
            const int cb = lane >> 4;
#pragma unroll
            for (int kb = 0; kb < 2; ++kb) {
                const int c = kb * 4 + cb;
                const int p = c ^ (q & 7);
                pfh[nf][kb] = *(const frag8*)&Ps[w][q * 128 + (p << 3)];
                pfl[nf][kb] = *(const frag8*)&Ps[w][q * 128 + ((p + 8) << 3)];
            }
        }
        __builtin_amdgcn_s_setprio(1);
#pragma unroll
        for (int df = 0; df < 4; ++df) {
            const int r = df * 16 + (lane & 15);
            const int cb = lane >> 4;
#pragma unroll
            for (int kb = 0; kb < 2; ++kb) {
                const int c = kb * 4 + cb;
                const int p = c ^ (r & 7);
                frag8 vfh = *(const frag8*)&Vs[r * 128 + (p << 3)];
                frag8 vfl = *(const frag8*)&Vs[r * 128 + ((p + 8) << 3)];
#pragma unroll
                for (int nf = 0; nf < 2; ++nf) {
                    acc[df][nf] = __builtin_amdgcn_mfma_f32_16x16x32_bf16(vfh, pfh[nf][kb], acc[df][nf], 0, 0, 0);
                    acc[df][nf] = __builtin_amdgcn_mfma_f32_16x16x32_bf16(vfh, pfl[nf][kb], acc[df][nf], 0, 0, 0);
                    acc[df][nf] = __builtin_amdgcn_mfma_f32_16x16x32_bf16(vfl, pfh[nf][kb], acc[df][nf], 0, 0, 0);
                }
            }
        }
        __builtin_amdgcn_s_setprio(0);

        __syncthreads();                          // all reads of Ks/Vs done
        if (kt < SEQ / 64 - 1) {
            stage_write();                        // T14: write late
            __syncthreads();
        }
    }

    // ---- epilogue: ctx as bf16 hi/lo, [b][s][h*64+d] ----
#pragma unroll
    for (int nf = 0; nf < 2; ++nf) {
        const float inv = 1.0f / l_run[nf];
        const int s = q0 + nf * 16 + (lane & 15);
#pragma unroll
        for (int df = 0; df < 4; ++df) {
            const int e0 = h * 64 + df * 16 + ((lane >> 4) << 2);
            ushort4 hi, lo;
            split2(acc[df][nf][0] * inv, hi.x, lo.x);
            split2(acc[df][nf][1] * inv, hi.y, lo.y);
            split2(acc[df][nf][2] * inv, hi.z, lo.z);
            split2(acc[df][nf][3] * inv, hi.w, lo.w);
            const size_t off = (size_t)(b * SEQ + s) * DM + e0;
            *(ushort4*)&ch[off] = hi;
            *(ushort4*)&cl[off] = lo;
        }
    }
}

extern "C" void kernel_launch(void* const* d_in, const int* in_sizes, int n_in,
                              void* d_out, int out_size, void* d_ws, size_t ws_size,
                              hipStream_t stream)
{
    const float* x  = (const float*)d_in[0];
    const int* mask = (const int*)d_in[1];
    const float* wq = (const float*)d_in[2];
    const float* bq = (const float*)d_in[3];
    const float* wk = (const float*)d_in[4];
    const float* bk = (const float*)d_in[5];
    const float* wv = (const float*)d_in[6];
    const float* bv = (const float*)d_in[7];
    const float* wo = (const float*)d_in[8];
    const float* bo = (const float*)d_in[9];
    float* out = (float*)d_out;

    const size_t M1 = 1024 * 1024;      // 1M elements
    ushort* W = (ushort*)d_ws;          // 80 MB arena
    ushort* xh = W;                     // 4M  (doubles as ctx_hi after attn)
    ushort* xl = W + 4 * M1;            // 4M  (ctx_lo)
    ushort* wh = W + 8 * M1;            // 4M: wq|wk|wv|wo
    ushort* wl = W + 12 * M1;
    ushort* Qh = W + 16 * M1;
    ushort* Ql = W + 20 * M1;
    ushort* Kh = W + 24 * M1;
    ushort* Kl = W + 28 * M1;
    ushort* Vh = W + 32 * M1;
    ushort* Vl = W + 36 * M1;           // ends at 40M ushorts = 80 MB

    split_all<<<2048, 256, 0, stream>>>(x, wq, wk, wv, wo, xh, xl, wh, wl);

    // fused QKV projection: A = [wq|wk|wv] (M=3072, 16 m-tiles of 192),
    // B = x (N=4096, 16 n-tiles of 256) -> 256 blocks, 8 waves
    gemm4<192, 256, 2, 4, 0><<<256, 512, 0, stream>>>(
        wh, wl, xh, xl, bq, bk, bv,
        Qh, Ql, Kh, Kl, Vh, Vl, nullptr, 16);

    attn_k<<<512, 256, 0, stream>>>(Qh, Ql, Kh, Kl, Vh, Vl, mask, xh, xl);

    // O-projection: A = wo (M=1024, 8 m-tiles of 128), B = ctx (= xh/xl,
    // N=4096, 32 n-tiles of 128) -> 256 blocks, 4 waves
    gemm4<128, 128, 2, 2, 1><<<256, 256, 0, stream>>>(
        wh + 3 * M1, wl + 3 * M1, xh, xl,
        bo, nullptr, nullptr,
        nullptr, nullptr, nullptr, nullptr, nullptr, nullptr, out, 8);
}